// Round 14
// baseline (122.982 us; speedup 1.0000x reference)
//
#include <hip/hip_runtime.h>

#define NB 4
#define HWN 4096
#define CD 64
#define NSTRIDE (HWN * CD)  // 262144 elems per batch in all swizzled buffers

typedef short short8 __attribute__((ext_vector_type(8), may_alias));
typedef short short4v __attribute__((ext_vector_type(4), may_alias));
typedef float f32x4 __attribute__((ext_vector_type(4), may_alias));

__device__ constexpr float C1 = 0.18033688011112042f; // log2(e)/8 (folded into Qs)

__device__ __forceinline__ unsigned short f2bf(float f) {
    unsigned u = __builtin_bit_cast(unsigned, f);
    u = (u + 0x7FFFu + ((u >> 16) & 1u)) >> 16;  // RTN-even
    return (unsigned short)u;
}

__device__ __forceinline__ float fexp2(float x) {
#if __has_builtin(__builtin_amdgcn_exp2f)
    return __builtin_amdgcn_exp2f(x);
#else
    return exp2f(x);
#endif
}

// Frag-major swizzle for a row-major [R][64] matrix, 16-row tiles:
// elem(row, c) -> tile = row>>4, half = c>>5, lane l = ((c>>3)&3)*16 + (row&15),
// offset = tile*1024 + half*512 + l*8 + (c&7).
__device__ __forceinline__ size_t qk_swz(int row, int c) {
    return (size_t)(row >> 4) * 1024 + (c >> 5) * 512 +
           ((((c >> 3) & 3) * 16 + (row & 15)) * 8) + (c & 7);
}

// ---------- prep: Qs = bf16(C1*Q) swizzled, Ks = bf16(K) swizzled ----------
__global__ __launch_bounds__(256) void cvt_qk(const float* __restrict__ Q,
                                              const float* __restrict__ K,
                                              unsigned short* __restrict__ Qs,
                                              unsigned short* __restrict__ Ks) {
    int i = (blockIdx.x * 256 + threadIdx.x) * 4;
    int rg = i >> 6, c = i & 63;
    int n = rg >> 12, r = rg & 4095;
    float4 q = *(const float4*)(Q + i);
    float4 k = *(const float4*)(K + i);
    ushort4 qo, ko;
    qo.x = f2bf(q.x * C1); qo.y = f2bf(q.y * C1);
    qo.z = f2bf(q.z * C1); qo.w = f2bf(q.w * C1);
    ko.x = f2bf(k.x); ko.y = f2bf(k.y); ko.z = f2bf(k.z); ko.w = f2bf(k.w);
    size_t off = (size_t)n * NSTRIDE + qk_swz(r, c);
    *(ushort4*)(Qs + off) = qo;
    *(ushort4*)(Ks + off) = ko;
}

// ---------- phase 1: l[n,k] = sum_q exp2(dot(C1*Q[q], K[k])) ----------
// Wave holds 64 stationary k (4 A-frag pairs); Q stream register-prefetched,
// shared by all 4 stationary tiles. grid (16 k-blocks of 256, NB, 16 q-slices).
__global__ __attribute__((amdgpu_flat_work_group_size(256, 256), amdgpu_waves_per_eu(2, 4)))
void lsum_kernel(const unsigned short* __restrict__ Qs,
                 const unsigned short* __restrict__ Ks,
                 float* __restrict__ l) {
    int tid = threadIdx.x;
    int w = tid >> 6, lane = tid & 63, quad = lane >> 4, m16 = lane & 15;
    int n = blockIdx.y;
    int kbase = blockIdx.x * 256 + w * 64;

    const unsigned short* Kp = Ks + (size_t)n * NSTRIDE + (kbase >> 4) * 1024 + lane * 8;
    short8 ka0 = *(const short8*)(Kp);
    short8 ka1 = *(const short8*)(Kp + 512);
    short8 kb0 = *(const short8*)(Kp + 1024);
    short8 kb1 = *(const short8*)(Kp + 1536);
    short8 kc0 = *(const short8*)(Kp + 2048);
    short8 kc1 = *(const short8*)(Kp + 2560);
    short8 kd0 = *(const short8*)(Kp + 3072);
    short8 kd1 = *(const short8*)(Kp + 3584);

    const unsigned short* Qp = Qs + (size_t)n * NSTRIDE + blockIdx.z * 16384 + lane * 8;

    short8 qc0 = *(const short8*)(Qp);
    short8 qc1 = *(const short8*)(Qp + 512);
    Qp += 1024;

    float lA[4] = {0.f, 0.f, 0.f, 0.f};
    float lB[4] = {0.f, 0.f, 0.f, 0.f};
    float lC[4] = {0.f, 0.f, 0.f, 0.f};
    float lD[4] = {0.f, 0.f, 0.f, 0.f};
#pragma unroll 2
    for (int qc = 0; qc < 16; ++qc) {
        short8 qn0 = *(const short8*)(Qp);        // prefetch next (overread at end: in-ws)
        short8 qn1 = *(const short8*)(Qp + 512);
        f32x4 a = {0.f, 0.f, 0.f, 0.f}, b = a, c = a, d = a;
        a = __builtin_amdgcn_mfma_f32_16x16x32_bf16(ka0, qc0, a, 0, 0, 0);
        a = __builtin_amdgcn_mfma_f32_16x16x32_bf16(ka1, qc1, a, 0, 0, 0);
        b = __builtin_amdgcn_mfma_f32_16x16x32_bf16(kb0, qc0, b, 0, 0, 0);
        b = __builtin_amdgcn_mfma_f32_16x16x32_bf16(kb1, qc1, b, 0, 0, 0);
        c = __builtin_amdgcn_mfma_f32_16x16x32_bf16(kc0, qc0, c, 0, 0, 0);
        c = __builtin_amdgcn_mfma_f32_16x16x32_bf16(kc1, qc1, c, 0, 0, 0);
        d = __builtin_amdgcn_mfma_f32_16x16x32_bf16(kd0, qc0, d, 0, 0, 0);
        d = __builtin_amdgcn_mfma_f32_16x16x32_bf16(kd1, qc1, d, 0, 0, 0);
#pragma unroll
        for (int r = 0; r < 4; ++r) {
            lA[r] += fexp2(a[r]);
            lB[r] += fexp2(b[r]);
            lC[r] += fexp2(c[r]);
            lD[r] += fexp2(d[r]);
        }
        qc0 = qn0; qc1 = qn1;
        Qp += 1024;
    }
#pragma unroll
    for (int r = 0; r < 4; ++r)
        for (int d1 = 1; d1 < 16; d1 <<= 1) {
            lA[r] += __shfl_xor(lA[r], d1);
            lB[r] += __shfl_xor(lB[r], d1);
            lC[r] += __shfl_xor(lC[r], d1);
            lD[r] += __shfl_xor(lD[r], d1);
        }
    if (m16 == 0) {
        float* lp = l + n * HWN + kbase + quad * 4;
#pragma unroll
        for (int r = 0; r < 4; ++r) {
            atomicAdd(lp + r, lA[r]);
            atomicAdd(lp + 16 + r, lB[r]);
            atomicAdd(lp + 32 + r, lC[r]);
            atomicAdd(lp + 48 + r, lD[r]);
        }
    }
}

// ---------- prep: Vts = K16-A-frag-major bf16(V[n][k][c] / l[n][k]) ----------
// Per 32-k block (2048 elems): 4 c-tiles of 16; lane l holds 8 shorts =
// [k16a: kb32*32 + quad*4 + j][c] (low4) and [k16b: +16] (high4), c = ct*16 + (l&15).
// offset = (k>>5)*2048 + ct*512 + l*8 + sub*4 + (k&3), quad = (l>>4)&3.
__global__ __launch_bounds__(256) void prep_v(const float* __restrict__ V,
                                              const float* __restrict__ l,
                                              unsigned short* __restrict__ Vts) {
    __shared__ float rl[64];
    __shared__ float tile[64][65];
    int tid = threadIdx.x, n = blockIdx.y, kbase = blockIdx.x * 64;
    if (tid < 64) rl[tid] = 1.0f / l[n * HWN + kbase + tid];
    __syncthreads();
#pragma unroll
    for (int i = 0; i < 16; ++i) {
        int e = i * 256 + tid;
        int k = e >> 6, c = e & 63;
        tile[c][k] = V[((size_t)(n * HWN + kbase + k)) * CD + c] * rl[k];
    }
    __syncthreads();
#pragma unroll
    for (int i = 0; i < 2; ++i) {
        int s = i * 256 + tid;        // 0..511
        int kb32 = s >> 8;            // 0..1 local 32k block
        int ct = (s >> 6) & 3;        // c-tile
        int ll = s & 63;              // dest lane
        int cc = ct * 16 + (ll & 15);
        int kq = ((ll >> 4) & 3) * 4; // quad*4
        int k0 = kb32 * 32 + kq;
        short8 v;
#pragma unroll
        for (int j = 0; j < 4; ++j) {
            v[j]     = (short)f2bf(tile[cc][k0 + j]);
            v[4 + j] = (short)f2bf(tile[cc][k0 + 16 + j]);
        }
        size_t off = (size_t)n * NSTRIDE + (size_t)((kbase >> 5) + kb32) * 2048 +
                     ct * 512 + ll * 8;
        *(short8*)(Vts + off) = v;
    }
}

// ---------- phase 2: out[q,c] = sum_k exp2(s'_kq) * V[k][c]/l[k] ----------
// grid (64 q-blocks of 64, NB, 4 k-slices). Wave w owns q-tile w*16.
// ZERO LDS: S' = K x Q (A=K, B=Q, K=32) exits in C-layout row=k(quad*4+r),
// col=q(m16) == the B-frag layout of mfma_f32_16x16x16_bf16. P = exp2(S')
// packs to short4 in registers and feeds PV directly:
//   outT[c][q] += mfma16(A = Vt-frag[c][k], B = P, acc).
// Out exits C-layout row=c-local, col=q -> contiguous float4 stores.
__global__ __attribute__((amdgpu_flat_work_group_size(256, 256), amdgpu_waves_per_eu(2, 4)))
void attn_kernel(const unsigned short* __restrict__ Qs,
                 const unsigned short* __restrict__ Ks,
                 const unsigned short* __restrict__ Vts,
                 float* __restrict__ partial,
                 int nit) {
    int tid = threadIdx.x;
    int w = tid >> 6, lane = tid & 63, quad = lane >> 4, m16 = lane & 15;
    int n = blockIdx.y;
    int qbase = blockIdx.x * 64 + w * 16;

    // Q B-frags: B[c = quad*8+j][q = m16] == frag-major layout, same as lsum
    const unsigned short* Qp = Qs + (size_t)n * NSTRIDE + (qbase >> 4) * 1024 + lane * 8;
    short8 qf0 = *(const short8*)(Qp);
    short8 qf1 = *(const short8*)(Qp + 512);

    size_t kofs = (size_t)blockIdx.z * (size_t)nit * 2048;  // 32k-chunk = 2048 elems
    const unsigned short* Kp = Ks + (size_t)n * NSTRIDE + kofs + lane * 8;
    const unsigned short* Vp = Vts + (size_t)n * NSTRIDE + kofs + lane * 8;

    f32x4 o[4];
#pragma unroll
    for (int ct = 0; ct < 4; ++ct) o[ct] = f32x4{0.f, 0.f, 0.f, 0.f};

#pragma unroll 2
    for (int it = 0; it < nit; ++it) {
        // K A-frags for two 16k tiles
        short8 kf00 = *(const short8*)(Kp);
        short8 kf01 = *(const short8*)(Kp + 512);
        short8 kf10 = *(const short8*)(Kp + 1024);
        short8 kf11 = *(const short8*)(Kp + 1536);
        // S' tiles: [16k x 16q] each, contraction c = 64
        f32x4 sA = {0.f, 0.f, 0.f, 0.f}, sB = sA;
        sA = __builtin_amdgcn_mfma_f32_16x16x32_bf16(kf00, qf0, sA, 0, 0, 0);
        sA = __builtin_amdgcn_mfma_f32_16x16x32_bf16(kf01, qf1, sA, 0, 0, 0);
        sB = __builtin_amdgcn_mfma_f32_16x16x32_bf16(kf10, qf0, sB, 0, 0, 0);
        sB = __builtin_amdgcn_mfma_f32_16x16x32_bf16(kf11, qf1, sB, 0, 0, 0);

        // P = exp2(S') -> B-frag registers (short4), no LDS
        short4v pA, pB;
#pragma unroll
        for (int r = 0; r < 4; ++r) {
            pA[r] = (short)f2bf(fexp2(sA[r]));
            pB[r] = (short)f2bf(fexp2(sB[r]));
        }

        // PV: per c-tile, one b128 V load gives both K=16 A-frags
#pragma unroll
        for (int ct = 0; ct < 4; ++ct) {
            short8 vf = *(const short8*)(Vp + ct * 512);
            short4v vlo = __builtin_shufflevector(vf, vf, 0, 1, 2, 3);
            short4v vhi = __builtin_shufflevector(vf, vf, 4, 5, 6, 7);
            o[ct] = __builtin_amdgcn_mfma_f32_16x16x16bf16_1k(vlo, pA, o[ct], 0, 0, 0);
            o[ct] = __builtin_amdgcn_mfma_f32_16x16x16bf16_1k(vhi, pB, o[ct], 0, 0, 0);
        }
        Kp += 2048;
        Vp += 2048;
    }

    // o[ct][r] = outT[c = ct*16 + quad*4 + r][q = qbase + m16] -> float4 stores
    float* pp = partial + (size_t)blockIdx.z * (NB * HWN * CD) +
                ((size_t)(n * HWN + qbase + m16)) * CD + quad * 4;
#pragma unroll
    for (int ct = 0; ct < 4; ++ct)
        *(f32x4*)(pp + ct * 16) = o[ct];
}

// ---------- final: out = sum of ns partial slices ----------
__global__ __launch_bounds__(256) void reduce_out(const float* __restrict__ p,
                                                  float* __restrict__ out, int ns) {
    int i = (blockIdx.x * 256 + threadIdx.x) * 4;
    f32x4 a = *(const f32x4*)(p + i);
    for (int s = 1; s < ns; ++s)
        a = a + *(const f32x4*)(p + (size_t)s * (NB * HWN * CD) + i);
    *(f32x4*)(out + i) = a;
}

extern "C" void kernel_launch(void* const* d_in, const int* in_sizes, int n_in,
                              void* d_out, int out_size, void* d_ws, size_t ws_size,
                              hipStream_t stream) {
    const float* Q = (const float*)d_in[0];
    const float* K = (const float*)d_in[1];
    const float* V = (const float*)d_in[2];
    float* out = (float*)d_out;

    char* ws = (char*)d_ws;
    unsigned short* Qs  = (unsigned short*)(ws);                   // 2 MB
    unsigned short* Ks  = (unsigned short*)(ws + (1u << 21));      // 2 MB
    unsigned short* Vts = (unsigned short*)(ws + (2u << 21));      // 2 MB
    float* l       = (float*)(ws + (3u << 21));                    // 64 KB
    float* partial = (float*)(ws + (4u << 21));                    // ns * 4 MB

    size_t base = (size_t)(4u << 21);
    size_t slice = (size_t)NB * HWN * CD * sizeof(float);
    int ns = (ws_size >= base + 4 * slice) ? 4 : 2;
    int nit = HWN / ns / 32;  // ns=4 -> 32 iters of 32k

    (void)hipMemsetAsync(l, 0, (size_t)NB * HWN * sizeof(float), stream);

    cvt_qk<<<1024, 256, 0, stream>>>(Q, K, Qs, Ks);
    lsum_kernel<<<dim3(16, NB, 16), 256, 0, stream>>>(Qs, Ks, l);
    prep_v<<<dim3(64, NB), 256, 0, stream>>>(V, l, Vts);
    attn_kernel<<<dim3(64, NB, ns), 256, 0, stream>>>(Qs, Ks, Vts, partial, nit);
    reduce_out<<<1024, 256, 0, stream>>>(partial, out, ns);
}

// Round 15
// 111.689 us; speedup vs baseline: 1.1011x; 1.1011x over previous
//
#include <hip/hip_runtime.h>
#include <hip/hip_bf16.h>

#define NB 4
#define HWN 4096
#define CD 64
#define NSTRIDE (HWN * CD)  // 262144 elems per batch in all swizzled buffers

typedef short short8 __attribute__((ext_vector_type(8), may_alias));
typedef short short4v __attribute__((ext_vector_type(4), may_alias));
typedef float f32x4 __attribute__((ext_vector_type(4), may_alias));

__device__ constexpr float C1 = 0.18033688011112042f; // log2(e)/8 (folded into Qs)

__device__ __forceinline__ unsigned short f2bf(float f) {
    unsigned u = __builtin_bit_cast(unsigned, f);
    u = (u + 0x7FFFu + ((u >> 16) & 1u)) >> 16;  // RTN-even
    return (unsigned short)u;
}

__device__ __forceinline__ float fexp2(float x) {
#if __has_builtin(__builtin_amdgcn_exp2f)
    return __builtin_amdgcn_exp2f(x);
#else
    return exp2f(x);
#endif
}

// pack two fp32 -> bf16x2 word (RN-even, same rounding as f2bf)
__device__ __forceinline__ unsigned pk2(float a, float b) {
    __hip_bfloat162 h = __float22bfloat162_rn(float2{a, b});
    unsigned u;
    __builtin_memcpy(&u, &h, 4);
    return u;
}

// Frag-major swizzle for a row-major [R][64] matrix, 16-row tiles:
// elem(row, c) -> tile = row>>4, half = c>>5, lane l = ((c>>3)&3)*16 + (row&15),
// offset = tile*1024 + half*512 + l*8 + (c&7).
__device__ __forceinline__ size_t qk_swz(int row, int c) {
    return (size_t)(row >> 4) * 1024 + (c >> 5) * 512 +
           ((((c >> 3) & 3) * 16 + (row & 15)) * 8) + (c & 7);
}

// ---------- prep: Qs = bf16(C1*Q) swizzled, Ks = bf16(K) swizzled ----------
__global__ __launch_bounds__(256) void cvt_qk(const float* __restrict__ Q,
                                              const float* __restrict__ K,
                                              unsigned short* __restrict__ Qs,
                                              unsigned short* __restrict__ Ks) {
    int i = (blockIdx.x * 256 + threadIdx.x) * 4;
    int rg = i >> 6, c = i & 63;
    int n = rg >> 12, r = rg & 4095;
    float4 q = *(const float4*)(Q + i);
    float4 k = *(const float4*)(K + i);
    ushort4 qo, ko;
    qo.x = f2bf(q.x * C1); qo.y = f2bf(q.y * C1);
    qo.z = f2bf(q.z * C1); qo.w = f2bf(q.w * C1);
    ko.x = f2bf(k.x); ko.y = f2bf(k.y); ko.z = f2bf(k.z); ko.w = f2bf(k.w);
    size_t off = (size_t)n * NSTRIDE + qk_swz(r, c);
    *(ushort4*)(Qs + off) = qo;
    *(ushort4*)(Ks + off) = ko;
}

// ---------- phase 1: l[n,k] = sum_q exp2(dot(C1*Q[q], K[k])) ----------
// Wave holds 64 stationary k (4 A-frag pairs); Q stream register-prefetched,
// shared by all 4 stationary tiles. grid (16 k-blocks of 256, NB, 16 q-slices).
__global__ __attribute__((amdgpu_flat_work_group_size(256, 256), amdgpu_waves_per_eu(2, 4)))
void lsum_kernel(const unsigned short* __restrict__ Qs,
                 const unsigned short* __restrict__ Ks,
                 float* __restrict__ l) {
    int tid = threadIdx.x;
    int w = tid >> 6, lane = tid & 63, quad = lane >> 4, m16 = lane & 15;
    int n = blockIdx.y;
    int kbase = blockIdx.x * 256 + w * 64;

    const unsigned short* Kp = Ks + (size_t)n * NSTRIDE + (kbase >> 4) * 1024 + lane * 8;
    short8 ka0 = *(const short8*)(Kp);
    short8 ka1 = *(const short8*)(Kp + 512);
    short8 kb0 = *(const short8*)(Kp + 1024);
    short8 kb1 = *(const short8*)(Kp + 1536);
    short8 kc0 = *(const short8*)(Kp + 2048);
    short8 kc1 = *(const short8*)(Kp + 2560);
    short8 kd0 = *(const short8*)(Kp + 3072);
    short8 kd1 = *(const short8*)(Kp + 3584);

    const unsigned short* Qp = Qs + (size_t)n * NSTRIDE + blockIdx.z * 16384 + lane * 8;

    short8 qc0 = *(const short8*)(Qp);
    short8 qc1 = *(const short8*)(Qp + 512);
    Qp += 1024;

    float lA[4] = {0.f, 0.f, 0.f, 0.f};
    float lB[4] = {0.f, 0.f, 0.f, 0.f};
    float lC[4] = {0.f, 0.f, 0.f, 0.f};
    float lD[4] = {0.f, 0.f, 0.f, 0.f};
#pragma unroll 2
    for (int qc = 0; qc < 16; ++qc) {
        short8 qn0 = *(const short8*)(Qp);        // prefetch next (overread at end: in-ws)
        short8 qn1 = *(const short8*)(Qp + 512);
        f32x4 a = {0.f, 0.f, 0.f, 0.f}, b = a, c = a, d = a;
        a = __builtin_amdgcn_mfma_f32_16x16x32_bf16(ka0, qc0, a, 0, 0, 0);
        a = __builtin_amdgcn_mfma_f32_16x16x32_bf16(ka1, qc1, a, 0, 0, 0);
        b = __builtin_amdgcn_mfma_f32_16x16x32_bf16(kb0, qc0, b, 0, 0, 0);
        b = __builtin_amdgcn_mfma_f32_16x16x32_bf16(kb1, qc1, b, 0, 0, 0);
        c = __builtin_amdgcn_mfma_f32_16x16x32_bf16(kc0, qc0, c, 0, 0, 0);
        c = __builtin_amdgcn_mfma_f32_16x16x32_bf16(kc1, qc1, c, 0, 0, 0);
        d = __builtin_amdgcn_mfma_f32_16x16x32_bf16(kd0, qc0, d, 0, 0, 0);
        d = __builtin_amdgcn_mfma_f32_16x16x32_bf16(kd1, qc1, d, 0, 0, 0);
#pragma unroll
        for (int r = 0; r < 4; ++r) {
            lA[r] += fexp2(a[r]);
            lB[r] += fexp2(b[r]);
            lC[r] += fexp2(c[r]);
            lD[r] += fexp2(d[r]);
        }
        qc0 = qn0; qc1 = qn1;
        Qp += 1024;
    }
#pragma unroll
    for (int r = 0; r < 4; ++r)
        for (int d1 = 1; d1 < 16; d1 <<= 1) {
            lA[r] += __shfl_xor(lA[r], d1);
            lB[r] += __shfl_xor(lB[r], d1);
            lC[r] += __shfl_xor(lC[r], d1);
            lD[r] += __shfl_xor(lD[r], d1);
        }
    if (m16 == 0) {
        float* lp = l + n * HWN + kbase + quad * 4;
#pragma unroll
        for (int r = 0; r < 4; ++r) {
            atomicAdd(lp + r, lA[r]);
            atomicAdd(lp + 16 + r, lB[r]);
            atomicAdd(lp + 32 + r, lC[r]);
            atomicAdd(lp + 48 + r, lD[r]);
        }
    }
}

// ---------- prep: Vts = K16-A-frag-major bf16(V[n][k][c] / l[n][k]) ----------
// Per 32-k block (2048 elems): 4 c-tiles of 16; lane l holds 8 shorts =
// A-frag[k16a: quad*4+j][c] (low4) and [k16b: +16] (high4), c = ct*16 + (l&15).
__global__ __launch_bounds__(256) void prep_v(const float* __restrict__ V,
                                              const float* __restrict__ l,
                                              unsigned short* __restrict__ Vts) {
    __shared__ float rl[64];
    __shared__ float tile[64][65];
    int tid = threadIdx.x, n = blockIdx.y, kbase = blockIdx.x * 64;
    if (tid < 64) rl[tid] = 1.0f / l[n * HWN + kbase + tid];
    __syncthreads();
#pragma unroll
    for (int i = 0; i < 16; ++i) {
        int e = i * 256 + tid;
        int k = e >> 6, c = e & 63;
        tile[c][k] = V[((size_t)(n * HWN + kbase + k)) * CD + c] * rl[k];
    }
    __syncthreads();
#pragma unroll
    for (int i = 0; i < 2; ++i) {
        int s = i * 256 + tid;        // 0..511
        int kb32 = s >> 8;            // 0..1 local 32k block
        int ct = (s >> 6) & 3;        // c-tile
        int ll = s & 63;              // dest lane
        int cc = ct * 16 + (ll & 15);
        int kq = ((ll >> 4) & 3) * 4; // quad*4
        int k0 = kb32 * 32 + kq;
        short8 v;
#pragma unroll
        for (int j = 0; j < 4; ++j) {
            v[j]     = (short)f2bf(tile[cc][k0 + j]);
            v[4 + j] = (short)f2bf(tile[cc][k0 + 16 + j]);
        }
        size_t off = (size_t)n * NSTRIDE + (size_t)((kbase >> 5) + kb32) * 2048 +
                     ct * 512 + ll * 8;
        *(short8*)(Vts + off) = v;
    }
}

// ---------- phase 2: out[q,c] = sum_k exp2(s'_kq) * V[k][c]/l[k] ----------
// grid (32 q-blocks of 128, NB, ns k-slices). Wave w owns TWO 16-q tiles
// (qbase, qbase+64) sharing every K/V load -> half the L2 traffic per FLOP.
// ZERO LDS: S' = K x Q C-layout == B-frag of mfma_f32_16x16x16_bf16; P packs
// in registers via v_cvt_pk and feeds PV directly. Out: contiguous f32x4.
__global__ __attribute__((amdgpu_flat_work_group_size(256, 256), amdgpu_waves_per_eu(2, 4)))
void attn_kernel(const unsigned short* __restrict__ Qs,
                 const unsigned short* __restrict__ Ks,
                 const unsigned short* __restrict__ Vts,
                 float* __restrict__ partial,
                 int nit) {
    int tid = threadIdx.x;
    int w = tid >> 6, lane = tid & 63, quad = lane >> 4, m16 = lane & 15;
    int n = blockIdx.y;
    int qbase = blockIdx.x * 128 + w * 16;   // second tile at +64

    const unsigned short* Qp = Qs + (size_t)n * NSTRIDE + (qbase >> 4) * 1024 + lane * 8;
    short8 qa0 = *(const short8*)(Qp);
    short8 qa1 = *(const short8*)(Qp + 512);
    short8 qb0 = *(const short8*)(Qp + 4096);        // +64 q rows = 4 frag tiles
    short8 qb1 = *(const short8*)(Qp + 4096 + 512);

    size_t kofs = (size_t)blockIdx.z * (size_t)nit * 2048;  // 32k-chunk = 2048 elems
    const unsigned short* Kp = Ks + (size_t)n * NSTRIDE + kofs + lane * 8;
    const unsigned short* Vp = Vts + (size_t)n * NSTRIDE + kofs + lane * 8;

    f32x4 oA[4], oB[4];
#pragma unroll
    for (int ct = 0; ct < 4; ++ct) { oA[ct] = f32x4{0.f, 0.f, 0.f, 0.f}; oB[ct] = oA[ct]; }

#pragma unroll 2
    for (int it = 0; it < nit; ++it) {
        // K A-frags for the two 16k tiles of this 32k chunk
        short8 kf00 = *(const short8*)(Kp);
        short8 kf01 = *(const short8*)(Kp + 512);
        short8 kf10 = *(const short8*)(Kp + 1024);
        short8 kf11 = *(const short8*)(Kp + 1536);
        // S' tiles [16k x 16q], contraction c=64; both q-tiles share K frags
        f32x4 s00 = {0.f, 0.f, 0.f, 0.f}, s01 = s00, s10 = s00, s11 = s00;
        s00 = __builtin_amdgcn_mfma_f32_16x16x32_bf16(kf00, qa0, s00, 0, 0, 0);
        s00 = __builtin_amdgcn_mfma_f32_16x16x32_bf16(kf01, qa1, s00, 0, 0, 0);
        s01 = __builtin_amdgcn_mfma_f32_16x16x32_bf16(kf10, qa0, s01, 0, 0, 0);
        s01 = __builtin_amdgcn_mfma_f32_16x16x32_bf16(kf11, qa1, s01, 0, 0, 0);
        s10 = __builtin_amdgcn_mfma_f32_16x16x32_bf16(kf00, qb0, s10, 0, 0, 0);
        s10 = __builtin_amdgcn_mfma_f32_16x16x32_bf16(kf01, qb1, s10, 0, 0, 0);
        s11 = __builtin_amdgcn_mfma_f32_16x16x32_bf16(kf10, qb0, s11, 0, 0, 0);
        s11 = __builtin_amdgcn_mfma_f32_16x16x32_bf16(kf11, qb1, s11, 0, 0, 0);

        // P = exp2(S') -> B-frag registers via packed cvt, no LDS
        uint2 w00, w01, w10, w11;
        w00.x = pk2(fexp2(s00[0]), fexp2(s00[1])); w00.y = pk2(fexp2(s00[2]), fexp2(s00[3]));
        w01.x = pk2(fexp2(s01[0]), fexp2(s01[1])); w01.y = pk2(fexp2(s01[2]), fexp2(s01[3]));
        w10.x = pk2(fexp2(s10[0]), fexp2(s10[1])); w10.y = pk2(fexp2(s10[2]), fexp2(s10[3]));
        w11.x = pk2(fexp2(s11[0]), fexp2(s11[1])); w11.y = pk2(fexp2(s11[2]), fexp2(s11[3]));
        short4v pA0 = __builtin_bit_cast(short4v, w00);  // tile A, k 0..15
        short4v pA1 = __builtin_bit_cast(short4v, w01);  // tile A, k 16..31
        short4v pB0 = __builtin_bit_cast(short4v, w10);
        short4v pB1 = __builtin_bit_cast(short4v, w11);

        // PV: per c-tile one b128 V load gives both K=16 A-frags; 2 q-tiles
#pragma unroll
        for (int ct = 0; ct < 4; ++ct) {
            short8 vf = *(const short8*)(Vp + ct * 512);
            short4v vlo = __builtin_shufflevector(vf, vf, 0, 1, 2, 3);
            short4v vhi = __builtin_shufflevector(vf, vf, 4, 5, 6, 7);
            oA[ct] = __builtin_amdgcn_mfma_f32_16x16x16bf16_1k(vlo, pA0, oA[ct], 0, 0, 0);
            oA[ct] = __builtin_amdgcn_mfma_f32_16x16x16bf16_1k(vhi, pA1, oA[ct], 0, 0, 0);
            oB[ct] = __builtin_amdgcn_mfma_f32_16x16x16bf16_1k(vlo, pB0, oB[ct], 0, 0, 0);
            oB[ct] = __builtin_amdgcn_mfma_f32_16x16x16bf16_1k(vhi, pB1, oB[ct], 0, 0, 0);
        }
        Kp += 2048;
        Vp += 2048;
    }

    // o{A,B}[ct][r] = outT[c = ct*16 + quad*4 + r][q] -> contiguous f32x4 stores
    float* ppA = partial + (size_t)blockIdx.z * (NB * HWN * CD) +
                 ((size_t)(n * HWN + qbase + m16)) * CD + quad * 4;
    float* ppB = ppA + (size_t)64 * CD;
#pragma unroll
    for (int ct = 0; ct < 4; ++ct) {
        *(f32x4*)(ppA + ct * 16) = oA[ct];
        *(f32x4*)(ppB + ct * 16) = oB[ct];
    }
}

// ---------- final: out = sum of ns partial slices ----------
__global__ __launch_bounds__(256) void reduce_out(const float* __restrict__ p,
                                                  float* __restrict__ out, int ns) {
    int i = (blockIdx.x * 256 + threadIdx.x) * 4;
    f32x4 a = *(const f32x4*)(p + i);
    for (int s = 1; s < ns; ++s)
        a = a + *(const f32x4*)(p + (size_t)s * (NB * HWN * CD) + i);
    *(f32x4*)(out + i) = a;
}

extern "C" void kernel_launch(void* const* d_in, const int* in_sizes, int n_in,
                              void* d_out, int out_size, void* d_ws, size_t ws_size,
                              hipStream_t stream) {
    const float* Q = (const float*)d_in[0];
    const float* K = (const float*)d_in[1];
    const float* V = (const float*)d_in[2];
    float* out = (float*)d_out;

    char* ws = (char*)d_ws;
    unsigned short* Qs  = (unsigned short*)(ws);                   // 2 MB
    unsigned short* Ks  = (unsigned short*)(ws + (1u << 21));      // 2 MB
    unsigned short* Vts = (unsigned short*)(ws + (2u << 21));      // 2 MB
    float* l       = (float*)(ws + (3u << 21));                    // 64 KB
    float* partial = (float*)(ws + (4u << 21));                    // ns * 4 MB

    size_t base = (size_t)(4u << 21);
    size_t slice = (size_t)NB * HWN * CD * sizeof(float);
    int ns = (ws_size >= base + 8 * slice) ? 8
           : (ws_size >= base + 4 * slice) ? 4 : 2;
    int nit = HWN / ns / 32;  // ns=8 -> 16 iters of 32k

    (void)hipMemsetAsync(l, 0, (size_t)NB * HWN * sizeof(float), stream);

    cvt_qk<<<1024, 256, 0, stream>>>(Q, K, Qs, Ks);
    lsum_kernel<<<dim3(16, NB, 16), 256, 0, stream>>>(Qs, Ks, l);
    prep_v<<<dim3(64, NB), 256, 0, stream>>>(V, l, Vts);
    attn_kernel<<<dim3(32, NB, ns), 256, 0, stream>>>(Qs, Ks, Vts, partial, nit);
    reduce_out<<<1024, 256, 0, stream>>>(partial, out, ns);
}